// Round 1
// baseline (364.142 us; speedup 1.0000x reference)
//
#include <hip/hip_runtime.h>

typedef float f32x2 __attribute__((ext_vector_type(2)));
typedef float f32x4 __attribute__((ext_vector_type(4)));

#define LOG2E 1.44269504088896340736f

__device__ __forceinline__ float rcp_fast(float x) { return __builtin_amdgcn_rcpf(x); }

__device__ __forceinline__ f32x2 mk2(float a, float b) { f32x2 v; v[0] = a; v[1] = b; return v; }

__device__ __forceinline__ float sigmoid_fast(float x) {
    // 1/(1+exp(-x)); exp2 overflow -> inf -> rcp -> 0 (correct limit), no NaN
    return rcp_fast(1.0f + __builtin_amdgcn_exp2f(-LOG2E * x));
}

__device__ __forceinline__ float tanh_fast(float x) {
    float a = __builtin_fabsf(x);
    float t = __builtin_amdgcn_exp2f(-2.0f * LOG2E * a);
    float r = (1.0f - t) * rcp_fast(1.0f + t);
    return __builtin_copysignf(r, x);
}

// Read 16 contiguous floats as 4x b128, emit 8 float2 pairs (works for LDS or global).
__device__ __forceinline__ void load_pairs16(const float* p, f32x2* dst) {
    const f32x4* q4 = (const f32x4*)p;
    f32x4 a = q4[0], b = q4[1], c = q4[2], d = q4[3];
    dst[0] = __builtin_shufflevector(a, a, 0, 1);
    dst[1] = __builtin_shufflevector(a, a, 2, 3);
    dst[2] = __builtin_shufflevector(b, b, 0, 1);
    dst[3] = __builtin_shufflevector(b, b, 2, 3);
    dst[4] = __builtin_shufflevector(c, c, 0, 1);
    dst[5] = __builtin_shufflevector(c, c, 2, 3);
    dst[6] = __builtin_shufflevector(d, d, 0, 1);
    dst[7] = __builtin_shufflevector(d, d, 2, 3);
}

// One wave (64 threads) = 4 batch elements; lane j in [0,16) = hidden index.
// W_in/LN folded into the gate weights at preamble (xh is only consumed by the
// gate matmul -> W_eff = W_ih @ W_in exactly). Two LDS broadcast rounds per
// step (h, x); h broadcast registers reused for both W_out and next-step gates.
// Block = 1 wave: NO __syncthreads anywhere (same-wave LDS ops are in-order;
// avoids vmcnt(0) drains of the output store in the recurrent chain).
// __launch_bounds__(64,2): grid gives only 2 waves/SIMD, so allow up to 256
// VGPRs -> all weights stay register-resident (no per-iteration reloads).
__global__ __launch_bounds__(64, 2) void vm_kernel(
    const float* __restrict__ init_state,  // (B,1,12)
    const float* __restrict__ commands,    // (B,T,4)
    const float* __restrict__ ln_g,        // (16)
    const float* __restrict__ ln_b,        // (16)
    const float* __restrict__ W_in,        // (16,16)
    const float* __restrict__ b_in,        // (16)
    const float* __restrict__ W_ih,        // (64,16)
    const float* __restrict__ W_hh,        // (64,16)
    const float* __restrict__ b_ih,        // (64)
    const float* __restrict__ b_hh,        // (64)
    const float* __restrict__ W_out,       // (12,16)
    const float* __restrict__ b_out,       // (12)
    float* __restrict__ out,               // (B,T,12)
    int B, int T)
{
    const int lane = threadIdx.x;
    const int j = lane & 15;
    const int g = lane >> 4;
    const int b = blockIdx.x * 4 + g;

    // stride 24 floats: b128 broadcast reads hit disjoint bank quads per group;
    // b32 writes <=2-way (free). 96B rows keep 16B alignment.
    __shared__ __align__(16) float sh_x[4][24];
    __shared__ __align__(16) float sh_h[4][24];

    // ---- preamble: load gate rows; W_ih transient, W_hh persistent ----
    f32x2 Wih[4][8], Wh[4][8];
#pragma unroll
    for (int q = 0; q < 4; ++q) {
        load_pairs16(W_ih + (q * 16 + j) * 16, Wih[q]);
        load_pairs16(W_hh + (q * 16 + j) * 16, Wh[q]);
    }

    // W_eff = W_ih @ W_in  (row q*16+j), plus bias fold
    f32x2 Wgx[4][8];
    float binacc[4];
#pragma unroll
    for (int q = 0; q < 4; ++q) {
        binacc[q] = 0.0f;
#pragma unroll
        for (int k2 = 0; k2 < 8; ++k2) Wgx[q][k2] = mk2(0.0f, 0.0f);
    }
#pragma unroll
    for (int m = 0; m < 16; ++m) {
        f32x2 wm[8];
        load_pairs16(W_in + m * 16, wm);   // uniform address -> scalar loads
        float bm = b_in[m];
#pragma unroll
        for (int q = 0; q < 4; ++q) {
            float wim = Wih[q][m >> 1][m & 1];
            f32x2 w2 = mk2(wim, wim);
#pragma unroll
            for (int k2 = 0; k2 < 8; ++k2) Wgx[q][k2] += w2 * wm[k2];
            binacc[q] += wim * bm;
        }
    }
    // fold LN gamma/beta: gate = (dot(Wgx,x) - mu*sg)*inv + cst + dot(Wh,h)
    float sg[4], cst[4];
    {
        f32x2 gg2[8], bt2[8];
        load_pairs16(ln_g, gg2);
        load_pairs16(ln_b, bt2);
#pragma unroll
        for (int q = 0; q < 4; ++q) {
            f32x2 ss = mk2(0.0f, 0.0f), cc = mk2(0.0f, 0.0f);
#pragma unroll
            for (int k2 = 0; k2 < 8; ++k2) {
                cc += Wgx[q][k2] * bt2[k2];
                Wgx[q][k2] *= gg2[k2];
                ss += Wgx[q][k2];
            }
            sg[q]  = ss[0] + ss[1];
            cst[q] = cc[0] + cc[1] + binacc[q] + b_ih[q * 16 + j] + b_hh[q * 16 + j];
        }
    }

    const bool is_state = (j < 12);
    f32x2 Wo[8];
    float bo = 0.0f;
#pragma unroll
    for (int k2 = 0; k2 < 8; ++k2) Wo[k2] = mk2(0.0f, 0.0f);
    if (is_state) {
        load_pairs16(W_out + j * 16, Wo);
        bo = b_out[j];
    }

    // ---- per-batch recurrent state ----
    float st = is_state ? init_state[b * 12 + j] : 0.0f;
    float c = 0.0f;
    f32x2 hp[8];
#pragma unroll
    for (int k2 = 0; k2 < 8; ++k2) hp[k2] = mk2(0.0f, 0.0f);

    const float* cmd_ptr = commands + (size_t)b * T * 4 + (j >= 12 ? j - 12 : 0);
    float* out_ptr = out + (size_t)b * T * 12 + j;

    // sincos partner lane within group: pairs (1,2),(3,4),(5,6)
    int pj = j;
    if (j >= 1 && j <= 6) pj = ((j - 1) ^ 1) + 1;
    const float* ppart = &sh_x[g][pj];
    const bool donorm = (j >= 1 && j <= 6);

    // ---- prologue: stage x0 = raw init state || cmd0 (ref: no initial norm) ----
    float cmd0 = (j >= 12) ? cmd_ptr[0] : 0.0f;
    sh_x[g][j] = is_state ? st : cmd0;
    f32x2 xp[8];
    load_pairs16(&sh_x[g][0], xp);

    float mu, inv;
    {
        f32x2 s2 = ((xp[0] + xp[1]) + (xp[2] + xp[3])) + ((xp[4] + xp[5]) + (xp[6] + xp[7]));
        float sum = s2[0] + s2[1];
        f32x2 qq = xp[0] * xp[0];
#pragma unroll
        for (int k2 = 1; k2 < 8; ++k2) qq += xp[k2] * xp[k2];
        float sumsq = qq[0] + qq[1];
        mu = sum * 0.0625f;
        float var = sumsq * 0.0625f - mu * mu;
        inv = __builtin_amdgcn_rsqf(var + 1e-5f);
    }

    // 2-deep command prefetch: cmdS = cmd_{t+1}, cmdN = cmd_{t+2}
    float cmdS = (j >= 12) ? cmd_ptr[4] : 0.0f;
    float cmdN = (j >= 12) ? cmd_ptr[8] : 0.0f;

    for (int t = 0; t < T; ++t) {
        // ---- gates (x part folded through W_in/LN; h from reused broadcast) ----
        f32x2 ai = Wgx[0][0] * xp[0], af = Wgx[1][0] * xp[0];
        f32x2 ag = Wgx[2][0] * xp[0], ao = Wgx[3][0] * xp[0];
        f32x2 hi = Wh[0][0] * hp[0], hf = Wh[1][0] * hp[0];
        f32x2 hg = Wh[2][0] * hp[0], ho = Wh[3][0] * hp[0];
#pragma unroll
        for (int k2 = 1; k2 < 8; ++k2) {
            ai += Wgx[0][k2] * xp[k2]; af += Wgx[1][k2] * xp[k2];
            ag += Wgx[2][k2] * xp[k2]; ao += Wgx[3][k2] * xp[k2];
            hi += Wh[0][k2] * hp[k2];  hf += Wh[1][k2] * hp[k2];
            hg += Wh[2][k2] * hp[k2];  ho += Wh[3][k2] * hp[k2];
        }
        float nmi = -mu * inv;
        float gi = __builtin_fmaf(ai[0] + ai[1], inv, __builtin_fmaf(nmi, sg[0], cst[0] + (hi[0] + hi[1])));
        float gf = __builtin_fmaf(af[0] + af[1], inv, __builtin_fmaf(nmi, sg[1], cst[1] + (hf[0] + hf[1])));
        float gG = __builtin_fmaf(ag[0] + ag[1], inv, __builtin_fmaf(nmi, sg[2], cst[2] + (hg[0] + hg[1])));
        float go = __builtin_fmaf(ao[0] + ao[1], inv, __builtin_fmaf(nmi, sg[3], cst[3] + (ho[0] + ho[1])));

        float iv = sigmoid_fast(gi);
        float fv = sigmoid_fast(gf);
        float gv = tanh_fast(gG);
        float ov = sigmoid_fast(go);
        c = fv * c + iv * gv;
        float hv = ov * tanh_fast(c);

        // ---- h round: single broadcast, reused for W_out now and gates next ----
        sh_h[g][j] = hv;
        load_pairs16(&sh_h[g][0], hp);

        f32x2 o2 = Wo[0] * hp[0];
#pragma unroll
        for (int k2 = 1; k2 < 8; ++k2) o2 += Wo[k2] * hp[k2];
        float st_raw = st + (o2[0] + o2[1]) + bo;   // j>=12: dead value

        // ---- x round: stage RAW state + next cmd; renorm after broadcast ----
        sh_x[g][j] = is_state ? st_raw : cmdS;
        float pv = *ppart;                 // partner raw (overlaps with b128 reads)
        load_pairs16(&sh_x[g][0], xp);

        // own sincos renorm (identical arithmetic to the xp-slot renorm below)
        float nrm = __builtin_amdgcn_sqrtf(st_raw * st_raw + pv * pv) + 1e-8f;
        float stn = st_raw * rcp_fast(nrm);
        st = donorm ? stn : st_raw;
        if (is_state) out_ptr[0] = st;
        out_ptr += 12;

        // renorm pairs (1,2),(3,4),(5,6) inside the broadcast vector
        {
            float a = xp[0][1], bq = xp[1][0];
            float r = rcp_fast(__builtin_amdgcn_sqrtf(a * a + bq * bq) + 1e-8f);
            xp[0][1] = a * r; xp[1][0] = bq * r;
        }
        {
            float a = xp[1][1], bq = xp[2][0];
            float r = rcp_fast(__builtin_amdgcn_sqrtf(a * a + bq * bq) + 1e-8f);
            xp[1][1] = a * r; xp[2][0] = bq * r;
        }
        {
            float a = xp[2][1], bq = xp[3][0];
            float r = rcp_fast(__builtin_amdgcn_sqrtf(a * a + bq * bq) + 1e-8f);
            xp[2][1] = a * r; xp[3][0] = bq * r;
        }

        // LN stats for next step
        f32x2 s2 = ((xp[0] + xp[1]) + (xp[2] + xp[3])) + ((xp[4] + xp[5]) + (xp[6] + xp[7]));
        float sum = s2[0] + s2[1];
        f32x2 qq = xp[0] * xp[0];
#pragma unroll
        for (int k2 = 1; k2 < 8; ++k2) qq += xp[k2] * xp[k2];
        float sumsq = qq[0] + qq[1];
        mu = sum * 0.0625f;
        float var = sumsq * 0.0625f - mu * mu;
        inv = __builtin_amdgcn_rsqf(var + 1e-5f);

        // rotate 2-deep cmd prefetch (load for t+3, clamped)
        cmdS = cmdN;
        int tn = t + 3;
        if (tn > T - 1) tn = T - 1;
        if (j >= 12) cmdN = cmd_ptr[(size_t)tn * 4];
    }
}

extern "C" void kernel_launch(void* const* d_in, const int* in_sizes, int n_in,
                              void* d_out, int out_size, void* d_ws, size_t ws_size,
                              hipStream_t stream) {
    const float* init_state = (const float*)d_in[0];
    const float* commands   = (const float*)d_in[1];
    const float* ln_g       = (const float*)d_in[2];
    const float* ln_b       = (const float*)d_in[3];
    const float* W_in       = (const float*)d_in[4];
    const float* b_in       = (const float*)d_in[5];
    const float* W_ih       = (const float*)d_in[6];
    const float* W_hh       = (const float*)d_in[7];
    const float* b_ih       = (const float*)d_in[8];
    const float* b_hh       = (const float*)d_in[9];
    const float* W_out      = (const float*)d_in[10];
    const float* b_out      = (const float*)d_in[11];

    int B = in_sizes[0] / 12;           // 8192
    int T = in_sizes[1] / (B * 4);      // 256

    int blocks = B / 4;                 // 4 batch elements per 64-thread block
    vm_kernel<<<blocks, 64, 0, stream>>>(init_state, commands, ln_g, ln_b,
                                         W_in, b_in, W_ih, W_hh, b_ih, b_hh,
                                         W_out, b_out, (float*)d_out, B, T);
}